// Round 5
// baseline (397.870 us; speedup 1.0000x reference)
//
#include <hip/hip_runtime.h>

#define N_NODES 65536
#define N_EDGES 1048576
#define DIM 64
#define M_POOL (N_NODES / DIM)  // 1024

#define NSLICE 64      // dst slices
#define SLICE  1024    // dsts per slice
#define NSUB   4       // sub-blocks per slice (each scans E/4 edges)
#define ESUB   (N_EDGES / NSUB)  // 262144

typedef unsigned int u32;
typedef unsigned short u16;

__device__ __forceinline__ float bf2f(u32 hi16) {
    return __uint_as_float(hi16 << 16);
}
__device__ __forceinline__ u32 f2bf(float f) {  // RNE
    u32 u = __float_as_uint(f);
    return (u + 0x7fffu + ((u >> 16) & 1u)) >> 16;
}

// ---------------- zero slice totals ----------------

__global__ void zero_tot(int* __restrict__ tot) {
    if (threadIdx.x < NSLICE) tot[threadIdx.x] = 0;
}

// ---------------- count: LDS histogram per (slice, sub-block) ---------------
// cnt2[slice][dl][sb]; tot[slice] += block's matched count

__global__ __launch_bounds__(256) void csr_count(const int* __restrict__ col,
                                                 int* __restrict__ cnt2,
                                                 int* __restrict__ tot) {
    __shared__ int scnt[SLICE];
    const int t = threadIdx.x;
    const int slice = blockIdx.x >> 2;
    const int sb = blockIdx.x & 3;
    for (int i = t; i < SLICE; i += 256) scnt[i] = 0;
    __syncthreads();

    const int lo = sb * ESUB;
    for (int e = lo + (t << 2); e < lo + ESUB; e += 1024) {
        const int4 c = *(const int4*)&col[e];
        if ((c.x >> 10) == slice) atomicAdd(&scnt[c.x & 1023], 1);
        if ((c.y >> 10) == slice) atomicAdd(&scnt[c.y & 1023], 1);
        if ((c.z >> 10) == slice) atomicAdd(&scnt[c.z & 1023], 1);
        if ((c.w >> 10) == slice) atomicAdd(&scnt[c.w & 1023], 1);
    }
    __syncthreads();

    int mysum = 0;
    for (int i = t; i < SLICE; i += 256) {
        cnt2[(slice << 12) | (i << 2) | sb] = scnt[i];
        mysum += scnt[i];
    }
#pragma unroll
    for (int off = 32; off > 0; off >>= 1) mysum += __shfl_down(mysum, off, 64);
    if ((t & 63) == 0) atomicAdd(&tot[slice], mysum);
}

// ---------------- scan stage A: exclusive scan of 64 slice totals -----------

__global__ void scan_base(const int* __restrict__ tot, int* __restrict__ base) {
    if (threadIdx.x == 0) {
        int s = 0;
        for (int i = 0; i < NSLICE; ++i) { base[i] = s; s += tot[i]; }
    }
}

// ---------------- scan stage B: per-slice exclusive scan of 4096 counts -----
// pbase[idx] = global exclusive prefix; rowptr[d] = pbase[d*4]

__global__ __launch_bounds__(256) void scan_write(const int* __restrict__ cnt2,
                                                  const int* __restrict__ base,
                                                  int* __restrict__ pbase,
                                                  int* __restrict__ rowptr) {
    __shared__ int part[256];
    const int b = blockIdx.x;   // slice
    const int t = threadIdx.x;
    const int idx0 = b * 4096 + t * 16;
    int v[16];
    int s = 0;
#pragma unroll
    for (int k = 0; k < 16; ++k) { v[k] = cnt2[idx0 + k]; s += v[k]; }
    part[t] = s;
    __syncthreads();
    for (int off = 1; off < 256; off <<= 1) {
        int val = (t >= off) ? part[t - off] : 0;
        __syncthreads();
        part[t] += val;
        __syncthreads();
    }
    int run = base[b] + ((t == 0) ? 0 : part[t - 1]);
#pragma unroll
    for (int k = 0; k < 16; ++k) {
        const int idx = idx0 + k;
        pbase[idx] = run;
        if ((idx & 3) == 0) rowptr[idx >> 2] = run;
        run += v[k];
    }
    if (b == NSLICE - 1 && t == 255) rowptr[N_NODES] = N_EDGES;
}

// ---------------- fill: LDS cursors, packed int2{src, ew_bits} --------------

__global__ __launch_bounds__(256) void csr_fill_s(const int* __restrict__ col,
                                                  const int* __restrict__ row,
                                                  const float* __restrict__ ew,
                                                  const int* __restrict__ pbase,
                                                  int2* __restrict__ csr) {
    __shared__ int cur[SLICE];
    const int t = threadIdx.x;
    const int slice = blockIdx.x >> 2;
    const int sb = blockIdx.x & 3;
    for (int i = t; i < SLICE; i += 256)
        cur[i] = pbase[(slice << 12) | (i << 2) | sb];
    __syncthreads();

    const int lo = sb * ESUB;
    for (int e = lo + (t << 2); e < lo + ESUB; e += 1024) {
        const int4 c = *(const int4*)&col[e];
#pragma unroll
        for (int k = 0; k < 4; ++k) {
            const int ck = (k == 0) ? c.x : (k == 1) ? c.y : (k == 2) ? c.z : c.w;
            if ((ck >> 10) == slice) {
                const int p = atomicAdd(&cur[ck & 1023], 1);
                csr[p] = make_int2(row[e + k], __float_as_int(ew[e + k]));
            }
        }
    }
}

// ---------------- dinv from CSR: dinv[c] = 1/sqrt(1 + sum ew) ---------------

__global__ __launch_bounds__(256) void deg_dinv(const int* __restrict__ rowptr,
                                                const int2* __restrict__ csr,
                                                float* __restrict__ dinv) {
    const int lane = threadIdx.x & 63;
    const int node = (blockIdx.x * 256 + threadIdx.x) >> 6;
    const int start = rowptr[node];
    const int end = rowptr[node + 1];
    float s = 0.f;
    for (int i = start + lane; i < end; i += 64)
        s += __int_as_float(csr[i].y);
#pragma unroll
    for (int off = 32; off > 0; off >>= 1) s += __shfl_down(s, off, 64);
    if (lane == 0) dinv[node] = 1.0f / sqrtf(1.0f + s);
}

// ---------------- GEMM: hb = bf16(xin @ W) ----------------------------------

__global__ __launch_bounds__(256) void gemm64(const float* __restrict__ xin,
                                              const float* __restrict__ W,
                                              u16* __restrict__ hb) {
    __shared__ float Ws[DIM * DIM];
    __shared__ float Xs[16][DIM];
    const int tid = threadIdx.x;
    const int row0 = blockIdx.x * 16;

    for (int i = tid; i < DIM * DIM; i += 256) Ws[i] = W[i];
    for (int i = tid; i < 16 * DIM; i += 256)
        Xs[i >> 6][i & 63] = xin[(row0 + (i >> 6)) * DIM + (i & 63)];
    __syncthreads();

    const int j = tid & 63;
    const int rs = tid >> 6;
    for (int rr = 0; rr < 4; ++rr) {
        const int r = rs * 4 + rr;
        float acc = 0.f;
#pragma unroll
        for (int k = 0; k < DIM; ++k) acc += Xs[r][k] * Ws[k * DIM + j];
        hb[(size_t)(row0 + r) * DIM + j] = (u16)f2bf(acc);
    }
}

// ---------------- aggregate layer 1 (bf16 gather) ---------------------------
// wave = 1 node; 8 edge-groups x 8 lanes; lane loads uint4 = 8 bf16 dims.
// out = bf16( sum(norm*h[src]) + dv^2*h[n] + b ); csr.y <- full norm.

__global__ __launch_bounds__(256) void aggregate_l1(const int* __restrict__ rowptr,
                                                    int2* __restrict__ csr,
                                                    const u16* __restrict__ hb,
                                                    const float* __restrict__ dinv,
                                                    const float* __restrict__ bias,
                                                    u16* __restrict__ ob) {
    const int lane = threadIdx.x & 63;
    const int node = (blockIdx.x * 256 + threadIdx.x) >> 6;
    const int g = lane >> 3;   // edge subgroup 0..7
    const int q = lane & 7;    // dim octet: dims q*8..q*8+7
    const int start = rowptr[node];
    const int end = rowptr[node + 1];
    const float dv = dinv[node];

    float acc[8];
#pragma unroll
    for (int k = 0; k < 8; ++k) acc[k] = 0.f;

    for (int i = start; i < end; i += 16) {
        const int i0 = i + g;
        const int i1 = i + 8 + g;
        const int2 v0 = (i0 < end) ? csr[i0] : make_int2(0, 0);
        const int2 v1 = (i1 < end) ? csr[i1] : make_int2(0, 0);
        const float w0 = __int_as_float(v0.y) * dinv[v0.x] * dv;
        const float w1 = __int_as_float(v1.y) * dinv[v1.x] * dv;
        if (q == 0) {  // cache full norm for layer 2
            if (i0 < end) csr[i0].y = __float_as_int(w0);
            if (i1 < end) csr[i1].y = __float_as_int(w1);
        }
        const uint4 B0 = *(const uint4*)&hb[(size_t)v0.x * DIM + q * 8];
        const uint4 B1 = *(const uint4*)&hb[(size_t)v1.x * DIM + q * 8];
        acc[0] += w0 * bf2f(B0.x & 0xffff) + w1 * bf2f(B1.x & 0xffff);
        acc[1] += w0 * bf2f(B0.x >> 16)    + w1 * bf2f(B1.x >> 16);
        acc[2] += w0 * bf2f(B0.y & 0xffff) + w1 * bf2f(B1.y & 0xffff);
        acc[3] += w0 * bf2f(B0.y >> 16)    + w1 * bf2f(B1.y >> 16);
        acc[4] += w0 * bf2f(B0.z & 0xffff) + w1 * bf2f(B1.z & 0xffff);
        acc[5] += w0 * bf2f(B0.z >> 16)    + w1 * bf2f(B1.z >> 16);
        acc[6] += w0 * bf2f(B0.w & 0xffff) + w1 * bf2f(B1.w & 0xffff);
        acc[7] += w0 * bf2f(B0.w >> 16)    + w1 * bf2f(B1.w >> 16);
    }
#pragma unroll
    for (int m = 8; m <= 32; m <<= 1) {
#pragma unroll
        for (int k = 0; k < 8; ++k) acc[k] += __shfl_xor(acc[k], m, 64);
    }
    if (lane < 8) {
        const uint4 S = *(const uint4*)&hb[(size_t)node * DIM + q * 8];
        const float dvv = dv * dv;
        float r[8];
        r[0] = acc[0] + dvv * bf2f(S.x & 0xffff) + bias[q * 8 + 0];
        r[1] = acc[1] + dvv * bf2f(S.x >> 16)    + bias[q * 8 + 1];
        r[2] = acc[2] + dvv * bf2f(S.y & 0xffff) + bias[q * 8 + 2];
        r[3] = acc[3] + dvv * bf2f(S.y >> 16)    + bias[q * 8 + 3];
        r[4] = acc[4] + dvv * bf2f(S.z & 0xffff) + bias[q * 8 + 4];
        r[5] = acc[5] + dvv * bf2f(S.z >> 16)    + bias[q * 8 + 5];
        r[6] = acc[6] + dvv * bf2f(S.w & 0xffff) + bias[q * 8 + 6];
        r[7] = acc[7] + dvv * bf2f(S.w >> 16)    + bias[q * 8 + 7];
        uint4 o;
        o.x = f2bf(r[0]) | (f2bf(r[1]) << 16);
        o.y = f2bf(r[2]) | (f2bf(r[3]) << 16);
        o.z = f2bf(r[4]) | (f2bf(r[5]) << 16);
        o.w = f2bf(r[6]) | (f2bf(r[7]) << 16);
        *(uint4*)&ob[(size_t)node * DIM + q * 8] = o;
    }
}

// ---------------- aggregate layer 2 (csr.y = full norm; no bias) ------------

__global__ __launch_bounds__(256) void aggregate_l2(const int* __restrict__ rowptr,
                                                    const int2* __restrict__ csr,
                                                    const u16* __restrict__ hb,
                                                    const float* __restrict__ dinv,
                                                    u16* __restrict__ ob) {
    const int lane = threadIdx.x & 63;
    const int node = (blockIdx.x * 256 + threadIdx.x) >> 6;
    const int g = lane >> 3;
    const int q = lane & 7;
    const int start = rowptr[node];
    const int end = rowptr[node + 1];

    float acc[8];
#pragma unroll
    for (int k = 0; k < 8; ++k) acc[k] = 0.f;

    for (int i = start; i < end; i += 16) {
        const int i0 = i + g;
        const int i1 = i + 8 + g;
        const int2 v0 = (i0 < end) ? csr[i0] : make_int2(0, 0);
        const int2 v1 = (i1 < end) ? csr[i1] : make_int2(0, 0);
        const float w0 = __int_as_float(v0.y);
        const float w1 = __int_as_float(v1.y);
        const uint4 B0 = *(const uint4*)&hb[(size_t)v0.x * DIM + q * 8];
        const uint4 B1 = *(const uint4*)&hb[(size_t)v1.x * DIM + q * 8];
        acc[0] += w0 * bf2f(B0.x & 0xffff) + w1 * bf2f(B1.x & 0xffff);
        acc[1] += w0 * bf2f(B0.x >> 16)    + w1 * bf2f(B1.x >> 16);
        acc[2] += w0 * bf2f(B0.y & 0xffff) + w1 * bf2f(B1.y & 0xffff);
        acc[3] += w0 * bf2f(B0.y >> 16)    + w1 * bf2f(B1.y >> 16);
        acc[4] += w0 * bf2f(B0.z & 0xffff) + w1 * bf2f(B1.z & 0xffff);
        acc[5] += w0 * bf2f(B0.z >> 16)    + w1 * bf2f(B1.z >> 16);
        acc[6] += w0 * bf2f(B0.w & 0xffff) + w1 * bf2f(B1.w & 0xffff);
        acc[7] += w0 * bf2f(B0.w >> 16)    + w1 * bf2f(B1.w >> 16);
    }
#pragma unroll
    for (int m = 8; m <= 32; m <<= 1) {
#pragma unroll
        for (int k = 0; k < 8; ++k) acc[k] += __shfl_xor(acc[k], m, 64);
    }
    if (lane < 8) {
        const float dv = dinv[node];
        const float dvv = dv * dv;
        const uint4 S = *(const uint4*)&hb[(size_t)node * DIM + q * 8];
        float r[8];
        r[0] = acc[0] + dvv * bf2f(S.x & 0xffff);
        r[1] = acc[1] + dvv * bf2f(S.x >> 16);
        r[2] = acc[2] + dvv * bf2f(S.y & 0xffff);
        r[3] = acc[3] + dvv * bf2f(S.y >> 16);
        r[4] = acc[4] + dvv * bf2f(S.z & 0xffff);
        r[5] = acc[5] + dvv * bf2f(S.z >> 16);
        r[6] = acc[6] + dvv * bf2f(S.w & 0xffff);
        r[7] = acc[7] + dvv * bf2f(S.w >> 16);
        uint4 o;
        o.x = f2bf(r[0]) | (f2bf(r[1]) << 16);
        o.y = f2bf(r[2]) | (f2bf(r[3]) << 16);
        o.z = f2bf(r[4]) | (f2bf(r[5]) << 16);
        o.w = f2bf(r[6]) | (f2bf(r[7]) << 16);
        *(uint4*)&ob[(size_t)node * DIM + q * 8] = o;
    }
}

// ---------------- fused pool + layer-2 GEMM ---------------------------------
// out[j][m] = (mean_w g[m*64+w][:]) @ W2[:,j] + b2[j]

__global__ __launch_bounds__(256) void pool_gemm(const u16* __restrict__ gb,
                                                 const float* __restrict__ W2,
                                                 const float* __restrict__ b2,
                                                 float* __restrict__ out) {
    __shared__ float Ws[DIM * DIM];
    __shared__ float pooled[4][DIM];
    const int t = threadIdx.x;
    for (int i = t; i < DIM * DIM; i += 256) Ws[i] = W2[i];
    const int wi = t >> 6;
    const int d = t & 63;
    const int m = blockIdx.x * 4 + wi;
    float s = 0.f;
#pragma unroll 8
    for (int w = 0; w < DIM; ++w)
        s += bf2f(gb[((size_t)m * DIM + w) * DIM + d]);
    pooled[wi][d] = s * (1.0f / DIM);
    __syncthreads();
    float acc = b2[d];
#pragma unroll
    for (int k = 0; k < DIM; ++k) acc += pooled[wi][k] * Ws[k * DIM + d];
    out[(size_t)d * M_POOL + m] = acc;
}

// ---------------- launcher --------------------------------------------------

extern "C" void kernel_launch(void* const* d_in, const int* in_sizes, int n_in,
                              void* d_out, int out_size, void* d_ws, size_t ws_size,
                              hipStream_t stream) {
    const float* x  = (const float*)d_in[0];
    const int*   ei = (const int*)d_in[1];   // [2][E]
    const float* ew = (const float*)d_in[2];
    const float* W1 = (const float*)d_in[3];
    const float* b1 = (const float*)d_in[4];
    const float* W2 = (const float*)d_in[5];
    const float* b2 = (const float*)d_in[6];
    float* out = (float*)d_out;

    char* w = (char*)d_ws;
    int*   cnt2   = (int*)w;   w += (size_t)262144 * 4;          // 1 MB
    int*   pbase  = (int*)w;   w += (size_t)262144 * 4;          // 1 MB
    int*   rowptr = (int*)w;   w += (size_t)(N_NODES + 16) * 4;
    int*   tot    = (int*)w;   w += 256;
    int*   base   = (int*)w;   w += 256;
    int2*  csr    = (int2*)w;  w += (size_t)N_EDGES * 8;         // 8 MB
    float* dinv   = (float*)w; w += (size_t)N_NODES * 4;
    u16*   hbf    = (u16*)w;   w += (size_t)N_NODES * DIM * 2;   // 8 MB
    u16*   h1bf   = (u16*)w;   w += (size_t)N_NODES * DIM * 2;   // 8 MB
    u16*   gbf    = (u16*)w;                                     // 8 MB

    const int* row = ei;             // edge_index[0]
    const int* col = ei + N_EDGES;   // edge_index[1]

    // CSR build — no global atomics on the edge stream
    zero_tot<<<1, 64, 0, stream>>>(tot);
    csr_count<<<NSLICE * NSUB, 256, 0, stream>>>(col, cnt2, tot);
    scan_base<<<1, 64, 0, stream>>>(tot, base);
    scan_write<<<NSLICE, 256, 0, stream>>>(cnt2, base, pbase, rowptr);
    csr_fill_s<<<NSLICE * NSUB, 256, 0, stream>>>(col, row, ew, pbase, csr);
    deg_dinv<<<N_NODES / 4, 256, 0, stream>>>(rowptr, csr, dinv);

    // layer 1: h = bf16(x@W1) ; h1 = bf16(A h + b1)  (caches norm in csr.y)
    gemm64<<<N_NODES / 16, 256, 0, stream>>>(x, W1, hbf);
    aggregate_l1<<<N_NODES / 4, 256, 0, stream>>>(rowptr, csr, hbf, dinv, b1, h1bf);

    // layer 2 (reordered): g = bf16(A h1) ; out = pool(g)@W2 + b2
    aggregate_l2<<<N_NODES / 4, 256, 0, stream>>>(rowptr, csr, h1bf, dinv, gbf);
    pool_gemm<<<M_POOL / 4, 256, 0, stream>>>(gbf, W2, b2, out);
}

// Round 6
// 215.073 us; speedup vs baseline: 1.8499x; 1.8499x over previous
//
#include <hip/hip_runtime.h>

#define N_NODES 65536
#define N_EDGES 1048576
#define DIM 64
#define M_POOL (N_NODES / DIM)  // 1024

typedef unsigned int u32;
typedef unsigned short u16;

__device__ __forceinline__ float bf2f(u32 hi16) {
    return __uint_as_float(hi16 << 16);
}
__device__ __forceinline__ u32 f2bf(float f) {  // RNE
    u32 u = __float_as_uint(f);
    return (u + 0x7fffu + ((u >> 16) & 1u)) >> 16;
}

// ---------------- zero in-degree counters ----------------

__global__ __launch_bounds__(256) void zero_cnt(int* __restrict__ cnt) {
    int i = blockIdx.x * 256 + threadIdx.x;
    if (i < N_NODES) cnt[i] = 0;
}

// ---------------- edge pass 1: in-degree histogram + per-edge bucket offset -

__global__ __launch_bounds__(256) void edge_pass1(const int* __restrict__ col,
                                                  int* __restrict__ cnt,
                                                  int* __restrict__ eoff) {
    int e = blockIdx.x * 256 + threadIdx.x;
    int stride = gridDim.x * 256;
    for (; e < N_EDGES; e += stride)
        eoff[e] = atomicAdd(&cnt[col[e]], 1);
}

// ---------------- exclusive scan of cnt[65536] -> rowptr[65537] -------------

__global__ __launch_bounds__(1024) void scan_counts(const int* __restrict__ cnt,
                                                    int* __restrict__ rowptr) {
    __shared__ int part[1024];
    const int t = threadIdx.x;
    const int base = t * 64;
    int s = 0;
    for (int i = 0; i < 64; ++i) s += cnt[base + i];
    part[t] = s;
    __syncthreads();
    for (int off = 1; off < 1024; off <<= 1) {
        int v = (t >= off) ? part[t - off] : 0;
        __syncthreads();
        part[t] += v;
        __syncthreads();
    }
    int offset = (t == 0) ? 0 : part[t - 1];
    for (int i = 0; i < 64; ++i) {
        rowptr[base + i] = offset;
        offset += cnt[base + i];
    }
    if (t == 1023) rowptr[N_NODES] = N_EDGES;
}

// ---------------- CSR fill — NO atomics, packed int2{src, ew_bits} ----------

__global__ __launch_bounds__(256) void csr_fill(const int* __restrict__ row,
                                                const int* __restrict__ col,
                                                const float* __restrict__ ew,
                                                const int* __restrict__ eoff,
                                                const int* __restrict__ rowptr,
                                                int2* __restrict__ csr) {
    int e = blockIdx.x * 256 + threadIdx.x;
    int stride = gridDim.x * 256;
    for (; e < N_EDGES; e += stride) {
        int c = col[e];
        int idx = rowptr[c] + eoff[e];
        csr[idx] = make_int2(row[e], __float_as_int(ew[e]));
    }
}

// ---------------- dinv from CSR: dinv[c] = 1/sqrt(1 + sum ew) ---------------

__global__ __launch_bounds__(256) void deg_dinv(const int* __restrict__ rowptr,
                                                const int2* __restrict__ csr,
                                                float* __restrict__ dinv) {
    const int lane = threadIdx.x & 63;
    const int node = (blockIdx.x * 256 + threadIdx.x) >> 6;
    const int start = rowptr[node];
    const int end = rowptr[node + 1];
    float s = 0.f;
    for (int i = start + lane; i < end; i += 64)
        s += __int_as_float(csr[i].y);
#pragma unroll
    for (int off = 32; off > 0; off >>= 1) s += __shfl_down(s, off, 64);
    if (lane == 0) dinv[node] = 1.0f / sqrtf(1.0f + s);
}

// ---------------- GEMM: hb = bf16(xin @ W) ----------------------------------

__global__ __launch_bounds__(256) void gemm64(const float* __restrict__ xin,
                                              const float* __restrict__ W,
                                              u16* __restrict__ hb) {
    __shared__ float Ws[DIM * DIM];
    __shared__ float Xs[16][DIM];
    const int tid = threadIdx.x;
    const int row0 = blockIdx.x * 16;

    for (int i = tid; i < DIM * DIM; i += 256) Ws[i] = W[i];
    for (int i = tid; i < 16 * DIM; i += 256)
        Xs[i >> 6][i & 63] = xin[(row0 + (i >> 6)) * DIM + (i & 63)];
    __syncthreads();

    const int j = tid & 63;
    const int rs = tid >> 6;
    for (int rr = 0; rr < 4; ++rr) {
        const int r = rs * 4 + rr;
        float acc = 0.f;
#pragma unroll
        for (int k = 0; k < DIM; ++k) acc += Xs[r][k] * Ws[k * DIM + j];
        hb[(size_t)(row0 + r) * DIM + j] = (u16)f2bf(acc);
    }
}

// ---------------- aggregate layer 1 (bf16 gather) ---------------------------
// wave = 1 node; 8 edge-groups x 8 lanes; lane loads uint4 = 8 bf16 dims.
// out = bf16( sum(norm*h[src]) + dv^2*h[n] + b ); csr.y <- full norm.

__global__ __launch_bounds__(256) void aggregate_l1(const int* __restrict__ rowptr,
                                                    int2* __restrict__ csr,
                                                    const u16* __restrict__ hb,
                                                    const float* __restrict__ dinv,
                                                    const float* __restrict__ bias,
                                                    u16* __restrict__ ob) {
    const int lane = threadIdx.x & 63;
    const int node = (blockIdx.x * 256 + threadIdx.x) >> 6;
    const int g = lane >> 3;   // edge subgroup 0..7
    const int q = lane & 7;    // dim octet: dims q*8..q*8+7
    const int start = rowptr[node];
    const int end = rowptr[node + 1];
    const float dv = dinv[node];

    float acc[8];
#pragma unroll
    for (int k = 0; k < 8; ++k) acc[k] = 0.f;

    for (int i = start; i < end; i += 16) {
        const int i0 = i + g;
        const int i1 = i + 8 + g;
        const int2 v0 = (i0 < end) ? csr[i0] : make_int2(0, 0);
        const int2 v1 = (i1 < end) ? csr[i1] : make_int2(0, 0);
        const float w0 = __int_as_float(v0.y) * dinv[v0.x] * dv;
        const float w1 = __int_as_float(v1.y) * dinv[v1.x] * dv;
        if (q == 0) {  // cache full norm for layer 2
            if (i0 < end) csr[i0].y = __float_as_int(w0);
            if (i1 < end) csr[i1].y = __float_as_int(w1);
        }
        const uint4 B0 = *(const uint4*)&hb[(size_t)v0.x * DIM + q * 8];
        const uint4 B1 = *(const uint4*)&hb[(size_t)v1.x * DIM + q * 8];
        acc[0] += w0 * bf2f(B0.x & 0xffff) + w1 * bf2f(B1.x & 0xffff);
        acc[1] += w0 * bf2f(B0.x >> 16)    + w1 * bf2f(B1.x >> 16);
        acc[2] += w0 * bf2f(B0.y & 0xffff) + w1 * bf2f(B1.y & 0xffff);
        acc[3] += w0 * bf2f(B0.y >> 16)    + w1 * bf2f(B1.y >> 16);
        acc[4] += w0 * bf2f(B0.z & 0xffff) + w1 * bf2f(B1.z & 0xffff);
        acc[5] += w0 * bf2f(B0.z >> 16)    + w1 * bf2f(B1.z >> 16);
        acc[6] += w0 * bf2f(B0.w & 0xffff) + w1 * bf2f(B1.w & 0xffff);
        acc[7] += w0 * bf2f(B0.w >> 16)    + w1 * bf2f(B1.w >> 16);
    }
#pragma unroll
    for (int m = 8; m <= 32; m <<= 1) {
#pragma unroll
        for (int k = 0; k < 8; ++k) acc[k] += __shfl_xor(acc[k], m, 64);
    }
    if (lane < 8) {
        const uint4 S = *(const uint4*)&hb[(size_t)node * DIM + q * 8];
        const float dvv = dv * dv;
        float r[8];
        r[0] = acc[0] + dvv * bf2f(S.x & 0xffff) + bias[q * 8 + 0];
        r[1] = acc[1] + dvv * bf2f(S.x >> 16)    + bias[q * 8 + 1];
        r[2] = acc[2] + dvv * bf2f(S.y & 0xffff) + bias[q * 8 + 2];
        r[3] = acc[3] + dvv * bf2f(S.y >> 16)    + bias[q * 8 + 3];
        r[4] = acc[4] + dvv * bf2f(S.z & 0xffff) + bias[q * 8 + 4];
        r[5] = acc[5] + dvv * bf2f(S.z >> 16)    + bias[q * 8 + 5];
        r[6] = acc[6] + dvv * bf2f(S.w & 0xffff) + bias[q * 8 + 6];
        r[7] = acc[7] + dvv * bf2f(S.w >> 16)    + bias[q * 8 + 7];
        uint4 o;
        o.x = f2bf(r[0]) | (f2bf(r[1]) << 16);
        o.y = f2bf(r[2]) | (f2bf(r[3]) << 16);
        o.z = f2bf(r[4]) | (f2bf(r[5]) << 16);
        o.w = f2bf(r[6]) | (f2bf(r[7]) << 16);
        *(uint4*)&ob[(size_t)node * DIM + q * 8] = o;
    }
}

// ---------------- aggregate layer 2 (csr.y = full norm; no bias) ------------

__global__ __launch_bounds__(256) void aggregate_l2(const int* __restrict__ rowptr,
                                                    const int2* __restrict__ csr,
                                                    const u16* __restrict__ hb,
                                                    const float* __restrict__ dinv,
                                                    u16* __restrict__ ob) {
    const int lane = threadIdx.x & 63;
    const int node = (blockIdx.x * 256 + threadIdx.x) >> 6;
    const int g = lane >> 3;
    const int q = lane & 7;
    const int start = rowptr[node];
    const int end = rowptr[node + 1];

    float acc[8];
#pragma unroll
    for (int k = 0; k < 8; ++k) acc[k] = 0.f;

    for (int i = start; i < end; i += 16) {
        const int i0 = i + g;
        const int i1 = i + 8 + g;
        const int2 v0 = (i0 < end) ? csr[i0] : make_int2(0, 0);
        const int2 v1 = (i1 < end) ? csr[i1] : make_int2(0, 0);
        const float w0 = __int_as_float(v0.y);
        const float w1 = __int_as_float(v1.y);
        const uint4 B0 = *(const uint4*)&hb[(size_t)v0.x * DIM + q * 8];
        const uint4 B1 = *(const uint4*)&hb[(size_t)v1.x * DIM + q * 8];
        acc[0] += w0 * bf2f(B0.x & 0xffff) + w1 * bf2f(B1.x & 0xffff);
        acc[1] += w0 * bf2f(B0.x >> 16)    + w1 * bf2f(B1.x >> 16);
        acc[2] += w0 * bf2f(B0.y & 0xffff) + w1 * bf2f(B1.y & 0xffff);
        acc[3] += w0 * bf2f(B0.y >> 16)    + w1 * bf2f(B1.y >> 16);
        acc[4] += w0 * bf2f(B0.z & 0xffff) + w1 * bf2f(B1.z & 0xffff);
        acc[5] += w0 * bf2f(B0.z >> 16)    + w1 * bf2f(B1.z >> 16);
        acc[6] += w0 * bf2f(B0.w & 0xffff) + w1 * bf2f(B1.w & 0xffff);
        acc[7] += w0 * bf2f(B0.w >> 16)    + w1 * bf2f(B1.w >> 16);
    }
#pragma unroll
    for (int m = 8; m <= 32; m <<= 1) {
#pragma unroll
        for (int k = 0; k < 8; ++k) acc[k] += __shfl_xor(acc[k], m, 64);
    }
    if (lane < 8) {
        const float dv = dinv[node];
        const float dvv = dv * dv;
        const uint4 S = *(const uint4*)&hb[(size_t)node * DIM + q * 8];
        float r[8];
        r[0] = acc[0] + dvv * bf2f(S.x & 0xffff);
        r[1] = acc[1] + dvv * bf2f(S.x >> 16);
        r[2] = acc[2] + dvv * bf2f(S.y & 0xffff);
        r[3] = acc[3] + dvv * bf2f(S.y >> 16);
        r[4] = acc[4] + dvv * bf2f(S.z & 0xffff);
        r[5] = acc[5] + dvv * bf2f(S.z >> 16);
        r[6] = acc[6] + dvv * bf2f(S.w & 0xffff);
        r[7] = acc[7] + dvv * bf2f(S.w >> 16);
        uint4 o;
        o.x = f2bf(r[0]) | (f2bf(r[1]) << 16);
        o.y = f2bf(r[2]) | (f2bf(r[3]) << 16);
        o.z = f2bf(r[4]) | (f2bf(r[5]) << 16);
        o.w = f2bf(r[6]) | (f2bf(r[7]) << 16);
        *(uint4*)&ob[(size_t)node * DIM + q * 8] = o;
    }
}

// ---------------- fused pool + layer-2 GEMM ---------------------------------
// out[j][m] = (mean_w g[m*64+w][:]) @ W2[:,j] + b2[j]

__global__ __launch_bounds__(256) void pool_gemm(const u16* __restrict__ gb,
                                                 const float* __restrict__ W2,
                                                 const float* __restrict__ b2,
                                                 float* __restrict__ out) {
    __shared__ float Ws[DIM * DIM];
    __shared__ float pooled[4][DIM];
    const int t = threadIdx.x;
    for (int i = t; i < DIM * DIM; i += 256) Ws[i] = W2[i];
    const int wi = t >> 6;
    const int d = t & 63;
    const int m = blockIdx.x * 4 + wi;
    float s = 0.f;
#pragma unroll 8
    for (int w = 0; w < DIM; ++w)
        s += bf2f(gb[((size_t)m * DIM + w) * DIM + d]);
    pooled[wi][d] = s * (1.0f / DIM);
    __syncthreads();
    float acc = b2[d];
#pragma unroll
    for (int k = 0; k < DIM; ++k) acc += pooled[wi][k] * Ws[k * DIM + d];
    out[(size_t)d * M_POOL + m] = acc;
}

// ---------------- launcher --------------------------------------------------

extern "C" void kernel_launch(void* const* d_in, const int* in_sizes, int n_in,
                              void* d_out, int out_size, void* d_ws, size_t ws_size,
                              hipStream_t stream) {
    const float* x  = (const float*)d_in[0];
    const int*   ei = (const int*)d_in[1];   // [2][E]
    const float* ew = (const float*)d_in[2];
    const float* W1 = (const float*)d_in[3];
    const float* b1 = (const float*)d_in[4];
    const float* W2 = (const float*)d_in[5];
    const float* b2 = (const float*)d_in[6];
    float* out = (float*)d_out;

    char* w = (char*)d_ws;
    int*   cnt    = (int*)w;   w += (size_t)N_NODES * 4;
    int*   rowptr = (int*)w;   w += (size_t)(N_NODES + 16) * 4;
    int*   eoff   = (int*)w;   w += (size_t)N_EDGES * 4;         // 4 MB
    int2*  csr    = (int2*)w;  w += (size_t)N_EDGES * 8;         // 8 MB
    float* dinv   = (float*)w; w += (size_t)N_NODES * 4;
    u16*   hbf    = (u16*)w;   w += (size_t)N_NODES * DIM * 2;   // 8 MB
    u16*   h1bf   = (u16*)w;   w += (size_t)N_NODES * DIM * 2;   // 8 MB
    u16*   gbf    = (u16*)w;                                     // 8 MB

    const int* row = ei;             // edge_index[0]
    const int* col = ei + N_EDGES;   // edge_index[1]

    // CSR build — 1 global atomic per edge
    zero_cnt<<<N_NODES / 256, 256, 0, stream>>>(cnt);
    edge_pass1<<<2048, 256, 0, stream>>>(col, cnt, eoff);
    scan_counts<<<1, 1024, 0, stream>>>(cnt, rowptr);
    csr_fill<<<2048, 256, 0, stream>>>(row, col, ew, eoff, rowptr, csr);
    deg_dinv<<<N_NODES / 4, 256, 0, stream>>>(rowptr, csr, dinv);

    // layer 1: h = bf16(x@W1) ; h1 = bf16(A h + b1)  (caches norm in csr.y)
    gemm64<<<N_NODES / 16, 256, 0, stream>>>(x, W1, hbf);
    aggregate_l1<<<N_NODES / 4, 256, 0, stream>>>(rowptr, csr, hbf, dinv, b1, h1bf);

    // layer 2 (reordered): g = bf16(A h1) ; out = pool(g)@W2 + b2
    aggregate_l2<<<N_NODES / 4, 256, 0, stream>>>(rowptr, csr, h1bf, dinv, gbf);
    pool_gemm<<<M_POOL / 4, 256, 0, stream>>>(gbf, W2, b2, out);
}

// Round 7
// 205.041 us; speedup vs baseline: 1.9404x; 1.0489x over previous
//
#include <hip/hip_runtime.h>

#define N_NODES 65536
#define N_EDGES 1048576
#define DIM 64
#define M_POOL (N_NODES / DIM)  // 1024
#define GEMM_BLOCKS 4096        // 65536/16
#define HIST_BLOCKS 1024        // 1048576/(256*4)

typedef unsigned int u32;
typedef unsigned short u16;

__device__ __forceinline__ float bf2f(u32 hi16) {
    return __uint_as_float(hi16 << 16);
}
__device__ __forceinline__ u32 f2bf(float f) {  // RNE
    u32 u = __float_as_uint(f);
    return (u + 0x7fffu + ((u >> 16) & 1u)) >> 16;
}

// ---------------- zero in-degree counters ----------------

__global__ __launch_bounds__(256) void zero_cnt(int* __restrict__ cnt) {
    int i = blockIdx.x * 256 + threadIdx.x;
    if (i < N_NODES) cnt[i] = 0;
}

// ---------------- fused: histogram (4-deep batched atomics) + layer-1 GEMM --
// 5120 blocks, interleaved 4 gemm : 1 hist so both kinds co-reside per CU.
// hist: eoff[e] = old count of col[e];  gemm: hb = bf16(x @ W1)

__global__ __launch_bounds__(256) void fused_hist_gemm(const int* __restrict__ col,
                                                       int* __restrict__ cnt,
                                                       int* __restrict__ eoff,
                                                       const float* __restrict__ x,
                                                       const float* __restrict__ W,
                                                       u16* __restrict__ hb) {
    __shared__ float Ws[DIM * DIM];
    __shared__ float Xs[16][DIM];
    const int tid = threadIdx.x;
    const int b = blockIdx.x;

    if ((b % 5) == 4) {
        // ---- histogram block (b/5 in 0..1023) ----
        const int t = (b / 5) * 256 + tid;
        const int e0 = t * 4;
        const int4 c = *(const int4*)&col[e0];
        int4 o;
        o.x = atomicAdd(&cnt[c.x], 1);
        o.y = atomicAdd(&cnt[c.y], 1);
        o.z = atomicAdd(&cnt[c.z], 1);
        o.w = atomicAdd(&cnt[c.w], 1);
        *(int4*)&eoff[e0] = o;
    } else {
        // ---- gemm block (b - b/5 in 0..4095) ----
        const int row0 = (b - b / 5) * 16;
        for (int i = tid; i < DIM * DIM; i += 256) Ws[i] = W[i];
        for (int i = tid; i < 16 * DIM; i += 256)
            Xs[i >> 6][i & 63] = x[(size_t)(row0 + (i >> 6)) * DIM + (i & 63)];
        __syncthreads();
        const int j = tid & 63;
        const int rs = tid >> 6;
        for (int rr = 0; rr < 4; ++rr) {
            const int r = rs * 4 + rr;
            float acc = 0.f;
#pragma unroll
            for (int k = 0; k < DIM; ++k) acc += Xs[r][k] * Ws[k * DIM + j];
            hb[(size_t)(row0 + r) * DIM + j] = (u16)f2bf(acc);
        }
    }
}

// ---------------- exclusive scan of cnt[65536] -> rowptr[65537] -------------

__global__ __launch_bounds__(1024) void scan_counts(const int* __restrict__ cnt,
                                                    int* __restrict__ rowptr) {
    __shared__ int part[1024];
    const int t = threadIdx.x;
    const int base = t * 64;
    int s = 0;
    for (int i = 0; i < 64; ++i) s += cnt[base + i];
    part[t] = s;
    __syncthreads();
    for (int off = 1; off < 1024; off <<= 1) {
        int v = (t >= off) ? part[t - off] : 0;
        __syncthreads();
        part[t] += v;
        __syncthreads();
    }
    int offset = (t == 0) ? 0 : part[t - 1];
    for (int i = 0; i < 64; ++i) {
        rowptr[base + i] = offset;
        offset += cnt[base + i];
    }
    if (t == 1023) rowptr[N_NODES] = N_EDGES;
}

// ---------------- CSR fill — no atomics, 4-deep batched ---------------------

__global__ __launch_bounds__(256) void csr_fill(const int* __restrict__ row,
                                                const int* __restrict__ col,
                                                const float* __restrict__ ew,
                                                const int* __restrict__ eoff,
                                                const int* __restrict__ rowptr,
                                                int2* __restrict__ csr) {
    const int t = blockIdx.x * 256 + threadIdx.x;  // grid 1024 blocks
    const int e0 = t * 4;
    const int4 c = *(const int4*)&col[e0];
    const int4 o = *(const int4*)&eoff[e0];
    const int4 r = *(const int4*)&row[e0];
    const float4 wv = *(const float4*)&ew[e0];
    csr[rowptr[c.x] + o.x] = make_int2(r.x, __float_as_int(wv.x));
    csr[rowptr[c.y] + o.y] = make_int2(r.y, __float_as_int(wv.y));
    csr[rowptr[c.z] + o.z] = make_int2(r.z, __float_as_int(wv.z));
    csr[rowptr[c.w] + o.w] = make_int2(r.w, __float_as_int(wv.w));
}

// ---------------- dinv from CSR: dinv[c] = 1/sqrt(1 + sum ew) ---------------

__global__ __launch_bounds__(256) void deg_dinv(const int* __restrict__ rowptr,
                                                const int2* __restrict__ csr,
                                                float* __restrict__ dinv) {
    const int lane = threadIdx.x & 63;
    const int node = (blockIdx.x * 256 + threadIdx.x) >> 6;
    const int start = rowptr[node];
    const int end = rowptr[node + 1];
    float s = 0.f;
    for (int i = start + lane; i < end; i += 64)
        s += __int_as_float(csr[i].y);
#pragma unroll
    for (int off = 32; off > 0; off >>= 1) s += __shfl_down(s, off, 64);
    if (lane == 0) dinv[node] = 1.0f / sqrtf(1.0f + s);
}

// ---------------- aggregate layer 1 (bf16 gather) ---------------------------
// wave = 1 node; 8 edge-groups x 8 lanes; lane loads uint4 = 8 bf16 dims.
// out = bf16( sum(norm*h[src]) + dv^2*h[n] + b ); csr.y <- full norm.

__global__ __launch_bounds__(256) void aggregate_l1(const int* __restrict__ rowptr,
                                                    int2* __restrict__ csr,
                                                    const u16* __restrict__ hb,
                                                    const float* __restrict__ dinv,
                                                    const float* __restrict__ bias,
                                                    u16* __restrict__ ob) {
    const int lane = threadIdx.x & 63;
    const int node = (blockIdx.x * 256 + threadIdx.x) >> 6;
    const int g = lane >> 3;   // edge subgroup 0..7
    const int q = lane & 7;    // dim octet: dims q*8..q*8+7
    const int start = rowptr[node];
    const int end = rowptr[node + 1];
    const float dv = dinv[node];

    float acc[8];
#pragma unroll
    for (int k = 0; k < 8; ++k) acc[k] = 0.f;

    for (int i = start; i < end; i += 16) {
        const int i0 = i + g;
        const int i1 = i + 8 + g;
        const int2 v0 = (i0 < end) ? csr[i0] : make_int2(0, 0);
        const int2 v1 = (i1 < end) ? csr[i1] : make_int2(0, 0);
        const float w0 = __int_as_float(v0.y) * dinv[v0.x] * dv;
        const float w1 = __int_as_float(v1.y) * dinv[v1.x] * dv;
        if (q == 0) {  // cache full norm for layer 2
            if (i0 < end) csr[i0].y = __float_as_int(w0);
            if (i1 < end) csr[i1].y = __float_as_int(w1);
        }
        const uint4 B0 = *(const uint4*)&hb[(size_t)v0.x * DIM + q * 8];
        const uint4 B1 = *(const uint4*)&hb[(size_t)v1.x * DIM + q * 8];
        acc[0] += w0 * bf2f(B0.x & 0xffff) + w1 * bf2f(B1.x & 0xffff);
        acc[1] += w0 * bf2f(B0.x >> 16)    + w1 * bf2f(B1.x >> 16);
        acc[2] += w0 * bf2f(B0.y & 0xffff) + w1 * bf2f(B1.y & 0xffff);
        acc[3] += w0 * bf2f(B0.y >> 16)    + w1 * bf2f(B1.y >> 16);
        acc[4] += w0 * bf2f(B0.z & 0xffff) + w1 * bf2f(B1.z & 0xffff);
        acc[5] += w0 * bf2f(B0.z >> 16)    + w1 * bf2f(B1.z >> 16);
        acc[6] += w0 * bf2f(B0.w & 0xffff) + w1 * bf2f(B1.w & 0xffff);
        acc[7] += w0 * bf2f(B0.w >> 16)    + w1 * bf2f(B1.w >> 16);
    }
#pragma unroll
    for (int m = 8; m <= 32; m <<= 1) {
#pragma unroll
        for (int k = 0; k < 8; ++k) acc[k] += __shfl_xor(acc[k], m, 64);
    }
    if (lane < 8) {
        const uint4 S = *(const uint4*)&hb[(size_t)node * DIM + q * 8];
        const float dvv = dv * dv;
        float r[8];
        r[0] = acc[0] + dvv * bf2f(S.x & 0xffff) + bias[q * 8 + 0];
        r[1] = acc[1] + dvv * bf2f(S.x >> 16)    + bias[q * 8 + 1];
        r[2] = acc[2] + dvv * bf2f(S.y & 0xffff) + bias[q * 8 + 2];
        r[3] = acc[3] + dvv * bf2f(S.y >> 16)    + bias[q * 8 + 3];
        r[4] = acc[4] + dvv * bf2f(S.z & 0xffff) + bias[q * 8 + 4];
        r[5] = acc[5] + dvv * bf2f(S.z >> 16)    + bias[q * 8 + 5];
        r[6] = acc[6] + dvv * bf2f(S.w & 0xffff) + bias[q * 8 + 6];
        r[7] = acc[7] + dvv * bf2f(S.w >> 16)    + bias[q * 8 + 7];
        uint4 o;
        o.x = f2bf(r[0]) | (f2bf(r[1]) << 16);
        o.y = f2bf(r[2]) | (f2bf(r[3]) << 16);
        o.z = f2bf(r[4]) | (f2bf(r[5]) << 16);
        o.w = f2bf(r[6]) | (f2bf(r[7]) << 16);
        *(uint4*)&ob[(size_t)node * DIM + q * 8] = o;
    }
}

// ---------------- fused: aggregate layer 2 + pooling + W2 GEMM --------------
// block = window m (64 nodes, CSR rows contiguous). Each wave accumulates 16
// nodes' messages in f32 regs (csr.y = cached full norm; self term via g==0),
// shfl+LDS reduce -> pooled[64], then out[:,m] = pooled @ W2 + b2.

__global__ __launch_bounds__(256) void agg2_pool_gemm(const int* __restrict__ rowptr,
                                                      const int2* __restrict__ csr,
                                                      const u16* __restrict__ hb,
                                                      const float* __restrict__ dinv,
                                                      const float* __restrict__ W2,
                                                      const float* __restrict__ b2,
                                                      float* __restrict__ out) {
    __shared__ float Ws[DIM * DIM];
    __shared__ float wacc[4][DIM];
    __shared__ float pooled[DIM];
    const int t = threadIdx.x;
    const int m = blockIdx.x;

    for (int i = t; i < DIM * DIM; i += 256) Ws[i] = W2[i];

    const int wave = t >> 6;
    const int lane = t & 63;
    const int g = lane >> 3;
    const int q = lane & 7;

    float acc[8];
#pragma unroll
    for (int k = 0; k < 8; ++k) acc[k] = 0.f;

    const int n0 = m * 64 + wave * 16;
    for (int nn = 0; nn < 16; ++nn) {
        const int node = n0 + nn;
        const int start = rowptr[node];
        const int end = rowptr[node + 1];
        for (int i = start; i < end; i += 16) {
            const int i0 = i + g;
            const int i1 = i + 8 + g;
            const int2 v0 = (i0 < end) ? csr[i0] : make_int2(0, 0);
            const int2 v1 = (i1 < end) ? csr[i1] : make_int2(0, 0);
            const float w0 = __int_as_float(v0.y);
            const float w1 = __int_as_float(v1.y);
            const uint4 B0 = *(const uint4*)&hb[(size_t)v0.x * DIM + q * 8];
            const uint4 B1 = *(const uint4*)&hb[(size_t)v1.x * DIM + q * 8];
            acc[0] += w0 * bf2f(B0.x & 0xffff) + w1 * bf2f(B1.x & 0xffff);
            acc[1] += w0 * bf2f(B0.x >> 16)    + w1 * bf2f(B1.x >> 16);
            acc[2] += w0 * bf2f(B0.y & 0xffff) + w1 * bf2f(B1.y & 0xffff);
            acc[3] += w0 * bf2f(B0.y >> 16)    + w1 * bf2f(B1.y >> 16);
            acc[4] += w0 * bf2f(B0.z & 0xffff) + w1 * bf2f(B1.z & 0xffff);
            acc[5] += w0 * bf2f(B0.z >> 16)    + w1 * bf2f(B1.z >> 16);
            acc[6] += w0 * bf2f(B0.w & 0xffff) + w1 * bf2f(B1.w & 0xffff);
            acc[7] += w0 * bf2f(B0.w >> 16)    + w1 * bf2f(B1.w >> 16);
        }
        if (g == 0) {  // self-loop term, counted once
            const float dv = dinv[node];
            const float dvv = dv * dv;
            const uint4 S = *(const uint4*)&hb[(size_t)node * DIM + q * 8];
            acc[0] += dvv * bf2f(S.x & 0xffff);
            acc[1] += dvv * bf2f(S.x >> 16);
            acc[2] += dvv * bf2f(S.y & 0xffff);
            acc[3] += dvv * bf2f(S.y >> 16);
            acc[4] += dvv * bf2f(S.z & 0xffff);
            acc[5] += dvv * bf2f(S.z >> 16);
            acc[6] += dvv * bf2f(S.w & 0xffff);
            acc[7] += dvv * bf2f(S.w >> 16);
        }
    }
#pragma unroll
    for (int mm = 8; mm <= 32; mm <<= 1) {
#pragma unroll
        for (int k = 0; k < 8; ++k) acc[k] += __shfl_xor(acc[k], mm, 64);
    }
    if (lane < 8) {
#pragma unroll
        for (int k = 0; k < 8; ++k) wacc[wave][q * 8 + k] = acc[k];
    }
    __syncthreads();
    if (t < DIM)
        pooled[t] = (wacc[0][t] + wacc[1][t] + wacc[2][t] + wacc[3][t]) * (1.0f / DIM);
    __syncthreads();
    if (t < DIM) {
        float o = b2[t];
#pragma unroll
        for (int k = 0; k < DIM; ++k) o += pooled[k] * Ws[k * DIM + t];
        out[(size_t)t * M_POOL + m] = o;
    }
}

// ---------------- launcher --------------------------------------------------

extern "C" void kernel_launch(void* const* d_in, const int* in_sizes, int n_in,
                              void* d_out, int out_size, void* d_ws, size_t ws_size,
                              hipStream_t stream) {
    const float* x  = (const float*)d_in[0];
    const int*   ei = (const int*)d_in[1];   // [2][E]
    const float* ew = (const float*)d_in[2];
    const float* W1 = (const float*)d_in[3];
    const float* b1 = (const float*)d_in[4];
    const float* W2 = (const float*)d_in[5];
    const float* b2 = (const float*)d_in[6];
    float* out = (float*)d_out;

    char* w = (char*)d_ws;
    int*   cnt    = (int*)w;   w += (size_t)N_NODES * 4;
    int*   rowptr = (int*)w;   w += (size_t)(N_NODES + 16) * 4;
    int*   eoff   = (int*)w;   w += (size_t)N_EDGES * 4;         // 4 MB
    int2*  csr    = (int2*)w;  w += (size_t)N_EDGES * 8;         // 8 MB
    float* dinv   = (float*)w; w += (size_t)N_NODES * 4;
    u16*   hbf    = (u16*)w;   w += (size_t)N_NODES * DIM * 2;   // 8 MB
    u16*   h1bf   = (u16*)w;                                     // 8 MB

    const int* row = ei;             // edge_index[0]
    const int* col = ei + N_EDGES;   // edge_index[1]

    // CSR build + layer-1 GEMM (independent -> fused heterogeneous grid)
    zero_cnt<<<N_NODES / 256, 256, 0, stream>>>(cnt);
    fused_hist_gemm<<<GEMM_BLOCKS + HIST_BLOCKS, 256, 0, stream>>>(
        col, cnt, eoff, x, W1, hbf);
    scan_counts<<<1, 1024, 0, stream>>>(cnt, rowptr);
    csr_fill<<<HIST_BLOCKS, 256, 0, stream>>>(row, col, ew, eoff, rowptr, csr);
    deg_dinv<<<N_NODES / 4, 256, 0, stream>>>(rowptr, csr, dinv);

    // layer 1 aggregate: h1 = bf16(A h + b1)   (caches norm in csr.y)
    aggregate_l1<<<N_NODES / 4, 256, 0, stream>>>(rowptr, csr, hbf, dinv, b1, h1bf);

    // layer 2 + pool + W2-GEMM fused per window
    agg2_pool_gemm<<<M_POOL, 256, 0, stream>>>(rowptr, csr, h1bf, dinv, W2, b2, out);
}

// Round 8
// 157.338 us; speedup vs baseline: 2.5288x; 1.3032x over previous
//
#include <hip/hip_runtime.h>

#define N_NODES 65536
#define N_EDGES 1048576
#define DIM 64
#define M_POOL (N_NODES / DIM)  // 1024
#define CAP 48                  // padded bucket capacity (mean deg 16 + 8 sigma)
#define GEMM_BLOCKS 4096        // 65536/16
#define HIST_BLOCKS 1024        // 1048576/(256*4)

typedef unsigned int u32;
typedef unsigned short u16;

__device__ __forceinline__ float bf2f(u32 hi16) {
    return __uint_as_float(hi16 << 16);
}
__device__ __forceinline__ u32 f2bf(float f) {  // RNE
    u32 u = __float_as_uint(f);
    return (u + 0x7fffu + ((u >> 16) & 1u)) >> 16;
}

// ---------------- zero bucket counters ----------------

__global__ __launch_bounds__(256) void zero_cnt(int* __restrict__ cnt) {
    int i = blockIdx.x * 256 + threadIdx.x;
    if (i < N_NODES) cnt[i] = 0;
}

// ---------------- fused: direct padded-bucket CSR build + layer-1 GEMM ------
// 5120 blocks, 4 gemm : 1 build interleave.
// build: p = atomicAdd(cnt[c]); csr[c*CAP+p] = {row, ew}   (no scan, no fill)
// gemm : hb = bf16(x @ W1)

__global__ __launch_bounds__(256) void fused_build_gemm(const int* __restrict__ col,
                                                        const int* __restrict__ row,
                                                        const float* __restrict__ ew,
                                                        int* __restrict__ cnt,
                                                        int2* __restrict__ csr,
                                                        const float* __restrict__ x,
                                                        const float* __restrict__ W,
                                                        u16* __restrict__ hb) {
    __shared__ float Ws[DIM * DIM];
    __shared__ float Xs[16][DIM];
    const int tid = threadIdx.x;
    const int b = blockIdx.x;

    if ((b % 5) == 4) {
        // ---- build block (b/5 in 0..1023) ----
        const int t = (b / 5) * 256 + tid;
        const int e0 = t * 4;
        const int4 c = *(const int4*)&col[e0];
        const int4 r = *(const int4*)&row[e0];
        const float4 wv = *(const float4*)&ew[e0];
        int p;
        p = atomicAdd(&cnt[c.x], 1);
        if (p < CAP) csr[c.x * CAP + p] = make_int2(r.x, __float_as_int(wv.x));
        p = atomicAdd(&cnt[c.y], 1);
        if (p < CAP) csr[c.y * CAP + p] = make_int2(r.y, __float_as_int(wv.y));
        p = atomicAdd(&cnt[c.z], 1);
        if (p < CAP) csr[c.z * CAP + p] = make_int2(r.z, __float_as_int(wv.z));
        p = atomicAdd(&cnt[c.w], 1);
        if (p < CAP) csr[c.w * CAP + p] = make_int2(r.w, __float_as_int(wv.w));
    } else {
        // ---- gemm block (b - b/5 in 0..4095) ----
        const int row0 = (b - b / 5) * 16;
        for (int i = tid; i < DIM * DIM; i += 256) Ws[i] = W[i];
        for (int i = tid; i < 16 * DIM; i += 256)
            Xs[i >> 6][i & 63] = x[(size_t)(row0 + (i >> 6)) * DIM + (i & 63)];
        __syncthreads();
        const int j = tid & 63;
        const int rs = tid >> 6;
        for (int rr = 0; rr < 4; ++rr) {
            const int r = rs * 4 + rr;
            float acc = 0.f;
#pragma unroll
            for (int k = 0; k < DIM; ++k) acc += Xs[r][k] * Ws[k * DIM + j];
            hb[(size_t)(row0 + r) * DIM + j] = (u16)f2bf(acc);
        }
    }
}

// ---------------- dinv: one predicated load (CAP <= 48 < 64 lanes) ----------

__global__ __launch_bounds__(256) void deg_dinv(const int* __restrict__ cnt,
                                                const int2* __restrict__ csr,
                                                float* __restrict__ dinv) {
    const int lane = threadIdx.x & 63;
    const int node = (blockIdx.x * 256 + threadIdx.x) >> 6;
    const int n = min(cnt[node], CAP);
    float s = (lane < n) ? __int_as_float(csr[node * CAP + lane].y) : 0.f;
#pragma unroll
    for (int off = 32; off > 0; off >>= 1) s += __shfl_down(s, off, 64);
    if (lane == 0) dinv[node] = 1.0f / sqrtf(1.0f + s);
}

// ---------------- aggregate layer 1 (bf16 gather, padded buckets) -----------
// wave = 1 node; 8 edge-groups x 8 lanes; lane loads uint4 = 8 bf16 dims.
// out = bf16( sum(norm*h[src]) + dv^2*h[n] + b ); csr.y <- full norm.

__global__ __launch_bounds__(256) void aggregate_l1(const int* __restrict__ cnt,
                                                    int2* __restrict__ csr,
                                                    const u16* __restrict__ hb,
                                                    const float* __restrict__ dinv,
                                                    const float* __restrict__ bias,
                                                    u16* __restrict__ ob) {
    const int lane = threadIdx.x & 63;
    const int node = (blockIdx.x * 256 + threadIdx.x) >> 6;
    const int g = lane >> 3;   // edge subgroup 0..7
    const int q = lane & 7;    // dim octet: dims q*8..q*8+7
    const int start = node * CAP;
    const int end = start + min(cnt[node], CAP);
    const float dv = dinv[node];

    float acc[8];
#pragma unroll
    for (int k = 0; k < 8; ++k) acc[k] = 0.f;

    for (int i = start; i < end; i += 16) {
        const int i0 = i + g;
        const int i1 = i + 8 + g;
        const int2 v0 = (i0 < end) ? csr[i0] : make_int2(0, 0);
        const int2 v1 = (i1 < end) ? csr[i1] : make_int2(0, 0);
        const float w0 = __int_as_float(v0.y) * dinv[v0.x] * dv;
        const float w1 = __int_as_float(v1.y) * dinv[v1.x] * dv;
        if (q == 0) {  // cache full norm for layer 2
            if (i0 < end) csr[i0].y = __float_as_int(w0);
            if (i1 < end) csr[i1].y = __float_as_int(w1);
        }
        const uint4 B0 = *(const uint4*)&hb[(size_t)v0.x * DIM + q * 8];
        const uint4 B1 = *(const uint4*)&hb[(size_t)v1.x * DIM + q * 8];
        acc[0] += w0 * bf2f(B0.x & 0xffff) + w1 * bf2f(B1.x & 0xffff);
        acc[1] += w0 * bf2f(B0.x >> 16)    + w1 * bf2f(B1.x >> 16);
        acc[2] += w0 * bf2f(B0.y & 0xffff) + w1 * bf2f(B1.y & 0xffff);
        acc[3] += w0 * bf2f(B0.y >> 16)    + w1 * bf2f(B1.y >> 16);
        acc[4] += w0 * bf2f(B0.z & 0xffff) + w1 * bf2f(B1.z & 0xffff);
        acc[5] += w0 * bf2f(B0.z >> 16)    + w1 * bf2f(B1.z >> 16);
        acc[6] += w0 * bf2f(B0.w & 0xffff) + w1 * bf2f(B1.w & 0xffff);
        acc[7] += w0 * bf2f(B0.w >> 16)    + w1 * bf2f(B1.w >> 16);
    }
#pragma unroll
    for (int m = 8; m <= 32; m <<= 1) {
#pragma unroll
        for (int k = 0; k < 8; ++k) acc[k] += __shfl_xor(acc[k], m, 64);
    }
    if (lane < 8) {
        const uint4 S = *(const uint4*)&hb[(size_t)node * DIM + q * 8];
        const float dvv = dv * dv;
        float r[8];
        r[0] = acc[0] + dvv * bf2f(S.x & 0xffff) + bias[q * 8 + 0];
        r[1] = acc[1] + dvv * bf2f(S.x >> 16)    + bias[q * 8 + 1];
        r[2] = acc[2] + dvv * bf2f(S.y & 0xffff) + bias[q * 8 + 2];
        r[3] = acc[3] + dvv * bf2f(S.y >> 16)    + bias[q * 8 + 3];
        r[4] = acc[4] + dvv * bf2f(S.z & 0xffff) + bias[q * 8 + 4];
        r[5] = acc[5] + dvv * bf2f(S.z >> 16)    + bias[q * 8 + 5];
        r[6] = acc[6] + dvv * bf2f(S.w & 0xffff) + bias[q * 8 + 6];
        r[7] = acc[7] + dvv * bf2f(S.w >> 16)    + bias[q * 8 + 7];
        uint4 o;
        o.x = f2bf(r[0]) | (f2bf(r[1]) << 16);
        o.y = f2bf(r[2]) | (f2bf(r[3]) << 16);
        o.z = f2bf(r[4]) | (f2bf(r[5]) << 16);
        o.w = f2bf(r[6]) | (f2bf(r[7]) << 16);
        *(uint4*)&ob[(size_t)node * DIM + q * 8] = o;
    }
}

// ---------------- fused: aggregate layer 2 + pooling + W2 GEMM --------------
// block = window m, 512 threads = 8 waves x 8 nodes. Accumulate in f32 regs,
// shfl+LDS reduce -> pooled[64], then out[:,m] = pooled @ W2 + b2.

__global__ __launch_bounds__(512) void agg2_pool_gemm(const int* __restrict__ cnt,
                                                      const int2* __restrict__ csr,
                                                      const u16* __restrict__ hb,
                                                      const float* __restrict__ dinv,
                                                      const float* __restrict__ W2,
                                                      const float* __restrict__ b2,
                                                      float* __restrict__ out) {
    __shared__ float Ws[DIM * DIM];
    __shared__ float wacc[8][DIM];
    __shared__ float pooled[DIM];
    const int t = threadIdx.x;
    const int m = blockIdx.x;

    for (int i = t; i < DIM * DIM; i += 512) Ws[i] = W2[i];

    const int wave = t >> 6;
    const int lane = t & 63;
    const int g = lane >> 3;
    const int q = lane & 7;

    float acc[8];
#pragma unroll
    for (int k = 0; k < 8; ++k) acc[k] = 0.f;

    const int n0 = m * 64 + wave * 8;
    for (int nn = 0; nn < 8; ++nn) {
        const int node = n0 + nn;
        const int start = node * CAP;
        const int end = start + min(cnt[node], CAP);
        for (int i = start; i < end; i += 16) {
            const int i0 = i + g;
            const int i1 = i + 8 + g;
            const int2 v0 = (i0 < end) ? csr[i0] : make_int2(0, 0);
            const int2 v1 = (i1 < end) ? csr[i1] : make_int2(0, 0);
            const float w0 = __int_as_float(v0.y);
            const float w1 = __int_as_float(v1.y);
            const uint4 B0 = *(const uint4*)&hb[(size_t)v0.x * DIM + q * 8];
            const uint4 B1 = *(const uint4*)&hb[(size_t)v1.x * DIM + q * 8];
            acc[0] += w0 * bf2f(B0.x & 0xffff) + w1 * bf2f(B1.x & 0xffff);
            acc[1] += w0 * bf2f(B0.x >> 16)    + w1 * bf2f(B1.x >> 16);
            acc[2] += w0 * bf2f(B0.y & 0xffff) + w1 * bf2f(B1.y & 0xffff);
            acc[3] += w0 * bf2f(B0.y >> 16)    + w1 * bf2f(B1.y >> 16);
            acc[4] += w0 * bf2f(B0.z & 0xffff) + w1 * bf2f(B1.z & 0xffff);
            acc[5] += w0 * bf2f(B0.z >> 16)    + w1 * bf2f(B1.z >> 16);
            acc[6] += w0 * bf2f(B0.w & 0xffff) + w1 * bf2f(B1.w & 0xffff);
            acc[7] += w0 * bf2f(B0.w >> 16)    + w1 * bf2f(B1.w >> 16);
        }
        if (g == 0) {  // self-loop term, counted once
            const float dv = dinv[node];
            const float dvv = dv * dv;
            const uint4 S = *(const uint4*)&hb[(size_t)node * DIM + q * 8];
            acc[0] += dvv * bf2f(S.x & 0xffff);
            acc[1] += dvv * bf2f(S.x >> 16);
            acc[2] += dvv * bf2f(S.y & 0xffff);
            acc[3] += dvv * bf2f(S.y >> 16);
            acc[4] += dvv * bf2f(S.z & 0xffff);
            acc[5] += dvv * bf2f(S.z >> 16);
            acc[6] += dvv * bf2f(S.w & 0xffff);
            acc[7] += dvv * bf2f(S.w >> 16);
        }
    }
#pragma unroll
    for (int mm = 8; mm <= 32; mm <<= 1) {
#pragma unroll
        for (int k = 0; k < 8; ++k) acc[k] += __shfl_xor(acc[k], mm, 64);
    }
    if (lane < 8) {
#pragma unroll
        for (int k = 0; k < 8; ++k) wacc[wave][q * 8 + k] = acc[k];
    }
    __syncthreads();
    if (t < DIM) {
        float p = 0.f;
#pragma unroll
        for (int w = 0; w < 8; ++w) p += wacc[w][t];
        pooled[t] = p * (1.0f / DIM);
    }
    __syncthreads();
    if (t < DIM) {
        float o = b2[t];
#pragma unroll
        for (int k = 0; k < DIM; ++k) o += pooled[k] * Ws[k * DIM + t];
        out[(size_t)t * M_POOL + m] = o;
    }
}

// ---------------- launcher --------------------------------------------------

extern "C" void kernel_launch(void* const* d_in, const int* in_sizes, int n_in,
                              void* d_out, int out_size, void* d_ws, size_t ws_size,
                              hipStream_t stream) {
    const float* x  = (const float*)d_in[0];
    const int*   ei = (const int*)d_in[1];   // [2][E]
    const float* ew = (const float*)d_in[2];
    const float* W1 = (const float*)d_in[3];
    const float* b1 = (const float*)d_in[4];
    const float* W2 = (const float*)d_in[5];
    const float* b2 = (const float*)d_in[6];
    float* out = (float*)d_out;

    char* w = (char*)d_ws;
    int*   cnt  = (int*)w;   w += (size_t)N_NODES * 4;            // 0.25 MB
    int2*  csr  = (int2*)w;  w += (size_t)N_NODES * CAP * 8;      // 24 MB
    float* dinv = (float*)w; w += (size_t)N_NODES * 4;            // 0.25 MB
    u16*   hbf  = (u16*)w;   w += (size_t)N_NODES * DIM * 2;      // 8 MB
    u16*   h1bf = (u16*)w;                                        // 8 MB

    const int* row = ei;             // edge_index[0]
    const int* col = ei + N_EDGES;   // edge_index[1]

    // build padded-bucket CSR + layer-1 GEMM in one heterogeneous grid
    zero_cnt<<<N_NODES / 256, 256, 0, stream>>>(cnt);
    fused_build_gemm<<<GEMM_BLOCKS + HIST_BLOCKS, 256, 0, stream>>>(
        col, row, ew, cnt, csr, x, W1, hbf);
    deg_dinv<<<N_NODES / 4, 256, 0, stream>>>(cnt, csr, dinv);

    // layer 1 aggregate: h1 = bf16(A h + b1)   (caches norm in csr.y)
    aggregate_l1<<<N_NODES / 4, 256, 0, stream>>>(cnt, csr, hbf, dinv, b1, h1bf);

    // layer 2 + pool + W2-GEMM fused per window
    agg2_pool_gemm<<<M_POOL, 512, 0, stream>>>(cnt, csr, h1bf, dinv, W2, b2, out);
}

// Round 9
// 154.099 us; speedup vs baseline: 2.5819x; 1.0210x over previous
//
#include <hip/hip_runtime.h>

#define N_NODES 65536
#define N_EDGES 1048576
#define DIM 64
#define M_POOL (N_NODES / DIM)  // 1024
#define CAP 48                  // padded bucket capacity (mean deg 16 + 8 sigma)
#define GEMM_BLOCKS 4096        // 65536/16
#define HIST_BLOCKS 512         // 1048576/(256*8)

typedef unsigned int u32;
typedef unsigned short u16;

__device__ __forceinline__ float bf2f(u32 hi16) {
    return __uint_as_float(hi16 << 16);
}
__device__ __forceinline__ u32 f2bf(float f) {  // RNE
    u32 u = __float_as_uint(f);
    return (u + 0x7fffu + ((u >> 16) & 1u)) >> 16;
}

// ---------------- zero bucket counters ----------------

__global__ __launch_bounds__(256) void zero_cnt(int* __restrict__ cnt) {
    int i = blockIdx.x * 256 + threadIdx.x;
    if (i < N_NODES) cnt[i] = 0;
}

// ---------------- fused: direct padded-bucket CSR build + layer-1 GEMM ------
// 4608 blocks, 8 gemm : 1 build interleave. Build threads own 8 edges each:
// 8 independent {atomic -> dependent store} chains in flight.

__global__ __launch_bounds__(256) void fused_build_gemm(const int* __restrict__ col,
                                                        const int* __restrict__ row,
                                                        const float* __restrict__ ew,
                                                        int* __restrict__ cnt,
                                                        int2* __restrict__ csr,
                                                        const float* __restrict__ x,
                                                        const float* __restrict__ W,
                                                        u16* __restrict__ hb) {
    __shared__ float Ws[DIM * DIM];
    __shared__ float Xs[16][DIM];
    const int tid = threadIdx.x;
    const int b = blockIdx.x;

    if ((b % 9) == 8) {
        // ---- build block (b/9 in 0..511) ----
        const int t = (b / 9) * 256 + tid;
        const int e0 = t * 8;
        const int4 c0 = *(const int4*)&col[e0];
        const int4 c1 = *(const int4*)&col[e0 + 4];
        const int4 r0 = *(const int4*)&row[e0];
        const int4 r1 = *(const int4*)&row[e0 + 4];
        const float4 w0 = *(const float4*)&ew[e0];
        const float4 w1 = *(const float4*)&ew[e0 + 4];
        int p;
        p = atomicAdd(&cnt[c0.x], 1);
        if (p < CAP) csr[c0.x * CAP + p] = make_int2(r0.x, __float_as_int(w0.x));
        p = atomicAdd(&cnt[c0.y], 1);
        if (p < CAP) csr[c0.y * CAP + p] = make_int2(r0.y, __float_as_int(w0.y));
        p = atomicAdd(&cnt[c0.z], 1);
        if (p < CAP) csr[c0.z * CAP + p] = make_int2(r0.z, __float_as_int(w0.z));
        p = atomicAdd(&cnt[c0.w], 1);
        if (p < CAP) csr[c0.w * CAP + p] = make_int2(r0.w, __float_as_int(w0.w));
        p = atomicAdd(&cnt[c1.x], 1);
        if (p < CAP) csr[c1.x * CAP + p] = make_int2(r1.x, __float_as_int(w1.x));
        p = atomicAdd(&cnt[c1.y], 1);
        if (p < CAP) csr[c1.y * CAP + p] = make_int2(r1.y, __float_as_int(w1.y));
        p = atomicAdd(&cnt[c1.z], 1);
        if (p < CAP) csr[c1.z * CAP + p] = make_int2(r1.z, __float_as_int(w1.z));
        p = atomicAdd(&cnt[c1.w], 1);
        if (p < CAP) csr[c1.w * CAP + p] = make_int2(r1.w, __float_as_int(w1.w));
    } else {
        // ---- gemm block (b - b/9 in 0..4095) ----
        const int row0 = (b - b / 9) * 16;
        for (int i = tid; i < DIM * DIM; i += 256) Ws[i] = W[i];
        for (int i = tid; i < 16 * DIM; i += 256)
            Xs[i >> 6][i & 63] = x[(size_t)(row0 + (i >> 6)) * DIM + (i & 63)];
        __syncthreads();
        const int j = tid & 63;
        const int rs = tid >> 6;
        for (int rr = 0; rr < 4; ++rr) {
            const int r = rs * 4 + rr;
            float acc = 0.f;
#pragma unroll
            for (int k = 0; k < DIM; ++k) acc += Xs[r][k] * Ws[k * DIM + j];
            hb[(size_t)(row0 + r) * DIM + j] = (u16)f2bf(acc);
        }
    }
}

// ---------------- dinv + in-place premultiply: hb <- dinv[n] * hb[n] --------
// wave = 1 node: bucket ew reduce -> dv; lanes 0..7 rescale the 128B hb row.

__global__ __launch_bounds__(256) void deg_dinv_premult(const int* __restrict__ cnt,
                                                        const int2* __restrict__ csr,
                                                        float* __restrict__ dinv,
                                                        u16* __restrict__ hb) {
    const int lane = threadIdx.x & 63;
    const int node = (blockIdx.x * 256 + threadIdx.x) >> 6;
    const int n = min(cnt[node], CAP);
    float s = (lane < n) ? __int_as_float(csr[node * CAP + lane].y) : 0.f;
#pragma unroll
    for (int off = 32; off > 0; off >>= 1) s += __shfl_down(s, off, 64);
    const float dv = 1.0f / sqrtf(1.0f + __shfl(s, 0, 64));
    if (lane == 0) dinv[node] = dv;
    if (lane < 8) {
        uint4 v = *(const uint4*)&hb[(size_t)node * DIM + lane * 8];
        uint4 o;
        o.x = f2bf(dv * bf2f(v.x & 0xffff)) | (f2bf(dv * bf2f(v.x >> 16)) << 16);
        o.y = f2bf(dv * bf2f(v.y & 0xffff)) | (f2bf(dv * bf2f(v.y >> 16)) << 16);
        o.z = f2bf(dv * bf2f(v.z & 0xffff)) | (f2bf(dv * bf2f(v.z >> 16)) << 16);
        o.w = f2bf(dv * bf2f(v.w & 0xffff)) | (f2bf(dv * bf2f(v.w >> 16)) << 16);
        *(uint4*)&hb[(size_t)node * DIM + lane * 8] = o;
    }
}

// ---------------- aggregate layer 1 (premultiplied tables, no dinv gather) --
// hb2[i] = dinv[i]*h[i].  h1 = sum((ew*dv)*hb2[r]) + dv*hb2[c] + b
// output h1p = bf16(dv * h1)  (premultiplied for layer 2)

__global__ __launch_bounds__(256) void aggregate_l1(const int* __restrict__ cnt,
                                                    const int2* __restrict__ csr,
                                                    const u16* __restrict__ hb2,
                                                    const float* __restrict__ dinv,
                                                    const float* __restrict__ bias,
                                                    u16* __restrict__ ob) {
    const int lane = threadIdx.x & 63;
    const int node = (blockIdx.x * 256 + threadIdx.x) >> 6;
    const int g = lane >> 3;   // edge subgroup 0..7
    const int q = lane & 7;    // dim octet
    const int start = node * CAP;
    const int end = start + min(cnt[node], CAP);
    const float dv = dinv[node];

    float acc[8];
#pragma unroll
    for (int k = 0; k < 8; ++k) acc[k] = 0.f;

    for (int i = start; i < end; i += 16) {
        const int i0 = i + g;
        const int i1 = i + 8 + g;
        const int2 v0 = (i0 < end) ? csr[i0] : make_int2(0, 0);
        const int2 v1 = (i1 < end) ? csr[i1] : make_int2(0, 0);
        const float w0 = __int_as_float(v0.y) * dv;
        const float w1 = __int_as_float(v1.y) * dv;
        const uint4 B0 = *(const uint4*)&hb2[(size_t)v0.x * DIM + q * 8];
        const uint4 B1 = *(const uint4*)&hb2[(size_t)v1.x * DIM + q * 8];
        acc[0] += w0 * bf2f(B0.x & 0xffff) + w1 * bf2f(B1.x & 0xffff);
        acc[1] += w0 * bf2f(B0.x >> 16)    + w1 * bf2f(B1.x >> 16);
        acc[2] += w0 * bf2f(B0.y & 0xffff) + w1 * bf2f(B1.y & 0xffff);
        acc[3] += w0 * bf2f(B0.y >> 16)    + w1 * bf2f(B1.y >> 16);
        acc[4] += w0 * bf2f(B0.z & 0xffff) + w1 * bf2f(B1.z & 0xffff);
        acc[5] += w0 * bf2f(B0.z >> 16)    + w1 * bf2f(B1.z >> 16);
        acc[6] += w0 * bf2f(B0.w & 0xffff) + w1 * bf2f(B1.w & 0xffff);
        acc[7] += w0 * bf2f(B0.w >> 16)    + w1 * bf2f(B1.w >> 16);
    }
#pragma unroll
    for (int m = 8; m <= 32; m <<= 1) {
#pragma unroll
        for (int k = 0; k < 8; ++k) acc[k] += __shfl_xor(acc[k], m, 64);
    }
    if (lane < 8) {
        const uint4 S = *(const uint4*)&hb2[(size_t)node * DIM + q * 8];
        float r[8];
        r[0] = dv * (acc[0] + dv * bf2f(S.x & 0xffff) + bias[q * 8 + 0]);
        r[1] = dv * (acc[1] + dv * bf2f(S.x >> 16)    + bias[q * 8 + 1]);
        r[2] = dv * (acc[2] + dv * bf2f(S.y & 0xffff) + bias[q * 8 + 2]);
        r[3] = dv * (acc[3] + dv * bf2f(S.y >> 16)    + bias[q * 8 + 3]);
        r[4] = dv * (acc[4] + dv * bf2f(S.z & 0xffff) + bias[q * 8 + 4]);
        r[5] = dv * (acc[5] + dv * bf2f(S.z >> 16)    + bias[q * 8 + 5]);
        r[6] = dv * (acc[6] + dv * bf2f(S.w & 0xffff) + bias[q * 8 + 6]);
        r[7] = dv * (acc[7] + dv * bf2f(S.w >> 16)    + bias[q * 8 + 7]);
        uint4 o;
        o.x = f2bf(r[0]) | (f2bf(r[1]) << 16);
        o.y = f2bf(r[2]) | (f2bf(r[3]) << 16);
        o.z = f2bf(r[4]) | (f2bf(r[5]) << 16);
        o.w = f2bf(r[6]) | (f2bf(r[7]) << 16);
        *(uint4*)&ob[(size_t)node * DIM + q * 8] = o;
    }
}

// ---------------- fused: aggregate layer 2 + pooling + W2 GEMM --------------
// block = window m, 512 threads = 8 waves x 8 nodes.
// agg2[c] = sum((ew*dv_c)*h1p[r]) + dv_c*h1p[c]  (h1p premultiplied)

__global__ __launch_bounds__(512) void agg2_pool_gemm(const int* __restrict__ cnt,
                                                      const int2* __restrict__ csr,
                                                      const u16* __restrict__ hb,
                                                      const float* __restrict__ dinv,
                                                      const float* __restrict__ W2,
                                                      const float* __restrict__ b2,
                                                      float* __restrict__ out) {
    __shared__ float Ws[DIM * DIM];
    __shared__ float wacc[8][DIM];
    __shared__ float pooled[DIM];
    const int t = threadIdx.x;
    const int m = blockIdx.x;

    for (int i = t; i < DIM * DIM; i += 512) Ws[i] = W2[i];

    const int wave = t >> 6;
    const int lane = t & 63;
    const int g = lane >> 3;
    const int q = lane & 7;

    float acc[8];
#pragma unroll
    for (int k = 0; k < 8; ++k) acc[k] = 0.f;

    const int n0 = m * 64 + wave * 8;
    for (int nn = 0; nn < 8; ++nn) {
        const int node = n0 + nn;
        const int start = node * CAP;
        const int end = start + min(cnt[node], CAP);
        const float dv = dinv[node];
        for (int i = start; i < end; i += 16) {
            const int i0 = i + g;
            const int i1 = i + 8 + g;
            const int2 v0 = (i0 < end) ? csr[i0] : make_int2(0, 0);
            const int2 v1 = (i1 < end) ? csr[i1] : make_int2(0, 0);
            const float w0 = __int_as_float(v0.y) * dv;
            const float w1 = __int_as_float(v1.y) * dv;
            const uint4 B0 = *(const uint4*)&hb[(size_t)v0.x * DIM + q * 8];
            const uint4 B1 = *(const uint4*)&hb[(size_t)v1.x * DIM + q * 8];
            acc[0] += w0 * bf2f(B0.x & 0xffff) + w1 * bf2f(B1.x & 0xffff);
            acc[1] += w0 * bf2f(B0.x >> 16)    + w1 * bf2f(B1.x >> 16);
            acc[2] += w0 * bf2f(B0.y & 0xffff) + w1 * bf2f(B1.y & 0xffff);
            acc[3] += w0 * bf2f(B0.y >> 16)    + w1 * bf2f(B1.y >> 16);
            acc[4] += w0 * bf2f(B0.z & 0xffff) + w1 * bf2f(B1.z & 0xffff);
            acc[5] += w0 * bf2f(B0.z >> 16)    + w1 * bf2f(B1.z >> 16);
            acc[6] += w0 * bf2f(B0.w & 0xffff) + w1 * bf2f(B1.w & 0xffff);
            acc[7] += w0 * bf2f(B0.w >> 16)    + w1 * bf2f(B1.w >> 16);
        }
        if (g == 0) {  // self-loop term: dv * h1p[node]
            const uint4 S = *(const uint4*)&hb[(size_t)node * DIM + q * 8];
            acc[0] += dv * bf2f(S.x & 0xffff);
            acc[1] += dv * bf2f(S.x >> 16);
            acc[2] += dv * bf2f(S.y & 0xffff);
            acc[3] += dv * bf2f(S.y >> 16);
            acc[4] += dv * bf2f(S.z & 0xffff);
            acc[5] += dv * bf2f(S.z >> 16);
            acc[6] += dv * bf2f(S.w & 0xffff);
            acc[7] += dv * bf2f(S.w >> 16);
        }
    }
#pragma unroll
    for (int mm = 8; mm <= 32; mm <<= 1) {
#pragma unroll
        for (int k = 0; k < 8; ++k) acc[k] += __shfl_xor(acc[k], mm, 64);
    }
    if (lane < 8) {
#pragma unroll
        for (int k = 0; k < 8; ++k) wacc[wave][q * 8 + k] = acc[k];
    }
    __syncthreads();
    if (t < DIM) {
        float p = 0.f;
#pragma unroll
        for (int w = 0; w < 8; ++w) p += wacc[w][t];
        pooled[t] = p * (1.0f / DIM);
    }
    __syncthreads();
    if (t < DIM) {
        float o = b2[t];
#pragma unroll
        for (int k = 0; k < DIM; ++k) o += pooled[k] * Ws[k * DIM + t];
        out[(size_t)t * M_POOL + m] = o;
    }
}

// ---------------- launcher --------------------------------------------------

extern "C" void kernel_launch(void* const* d_in, const int* in_sizes, int n_in,
                              void* d_out, int out_size, void* d_ws, size_t ws_size,
                              hipStream_t stream) {
    const float* x  = (const float*)d_in[0];
    const int*   ei = (const int*)d_in[1];   // [2][E]
    const float* ew = (const float*)d_in[2];
    const float* W1 = (const float*)d_in[3];
    const float* b1 = (const float*)d_in[4];
    const float* W2 = (const float*)d_in[5];
    const float* b2 = (const float*)d_in[6];
    float* out = (float*)d_out;

    char* w = (char*)d_ws;
    int*   cnt  = (int*)w;   w += (size_t)N_NODES * 4;            // 0.25 MB
    int2*  csr  = (int2*)w;  w += (size_t)N_NODES * CAP * 8;      // 24 MB
    float* dinv = (float*)w; w += (size_t)N_NODES * 4;            // 0.25 MB
    u16*   hbf  = (u16*)w;   w += (size_t)N_NODES * DIM * 2;      // 8 MB
    u16*   h1bf = (u16*)w;                                        // 8 MB

    const int* row = ei;             // edge_index[0]
    const int* col = ei + N_EDGES;   // edge_index[1]

    // build padded-bucket CSR + layer-1 GEMM in one heterogeneous grid
    zero_cnt<<<N_NODES / 256, 256, 0, stream>>>(cnt);
    fused_build_gemm<<<GEMM_BLOCKS + HIST_BLOCKS, 256, 0, stream>>>(
        col, row, ew, cnt, csr, x, W1, hbf);
    // dv + in-place premultiply hbf <- dinv * hbf
    deg_dinv_premult<<<N_NODES / 4, 256, 0, stream>>>(cnt, csr, dinv, hbf);

    // layer 1 aggregate: h1p = bf16(dv * (A h + b1))   (premultiplied)
    aggregate_l1<<<N_NODES / 4, 256, 0, stream>>>(cnt, csr, hbf, dinv, b1, h1bf);

    // layer 2 + pool + W2-GEMM fused per window
    agg2_pool_gemm<<<M_POOL, 512, 0, stream>>>(cnt, csr, h1bf, dinv, W2, b2, out);
}